// Round 1
// baseline (1020.817 us; speedup 1.0000x reference)
//
#include <hip/hip_runtime.h>
#include <math.h>

#define BB 256
#define II 2048
#define CC 10
#define DIN 8
#define DOUT 16
#define COW 160          // C*DOUT
#define BT 64            // b per block
#define NISPLIT 64
#define LEN 32           // II / NISPLIT
#define CHUNK 8
#define NCHUNK (LEN / CHUNK)
#define NTHR 640         // BT * CC

#define A_STRIDE 81      // CHUNK*CC + 1  (gcd(81,32) pattern -> conflict-free)
#define V_STRIDE 161     // COW + 1

__device__ __forceinline__ float dot8(const float4& a0, const float4& a1,
                                      const float4& b0, const float4& b1) {
    return a0.x*b0.x + a0.y*b0.y + a0.z*b0.z + a0.w*b0.w
         + a1.x*b1.x + a1.y*b1.y + a1.z*b1.z + a1.w*b1.w;
}

// MODE 0: iter0 (c_ij = 0.1 uniform), no routing phase.
// MODE 1: iter1 (a = uh.v0, softmax, weighted accumulate)
// MODE 2: iter2 (a = uh.(v0+v1) == a0+a1, softmax, weighted accumulate)
template<int MODE>
__global__ __launch_bounds__(NTHR)
void caps_pass(const float* __restrict__ u, const float* __restrict__ W,
               const float* __restrict__ v0, const float* __restrict__ v1,
               float* __restrict__ s)
{
    __shared__ float vs_lds[BT * V_STRIDE];  // v (or v0+v1) for block's 64 b's
    __shared__ float a_lds[BT * A_STRIDE];   // a[b][ic][c] -> overwritten by cij

    const int tid = threadIdx.x;
    const int bl  = tid & 63;        // b lane (wave = 64 b's, wave-uniform c)
    const int c   = tid >> 6;        // 0..9 capsule owner
    const int b   = blockIdx.y * BT + bl;
    const int i0  = blockIdx.x * LEN;

    if constexpr (MODE >= 1) {
        for (int f = tid; f < BT * COW; f += NTHR) {
            int fb = f / COW, fco = f % COW;
            int gidx = (blockIdx.y * BT + fb) * COW + fco;
            float x = v0[gidx];
            if constexpr (MODE == 2) x += v1[gidx];
            vs_lds[fb * V_STRIDE + fco] = x;
        }
        __syncthreads();
    }

    float acc[DOUT];
#pragma unroll
    for (int o = 0; o < DOUT; ++o) acc[o] = 0.f;

    const float4* u4 = (const float4*)u;
    const float4* W4 = (const float4*)W;

    for (int ch = 0; ch < NCHUNK; ++ch) {
        const int ibase = i0 + ch * CHUNK;

        if constexpr (MODE >= 1) {
            // Phase A: agreement a[b,i,c] = sum_o uh * v   (thread owns all o of its c)
            for (int ic = 0; ic < CHUNK; ++ic) {
                const int i = ibase + ic;
                const float4 ua = u4[(b * II + i) * 2 + 0];
                const float4 ub = u4[(b * II + i) * 2 + 1];
                const float4* wp = W4 + (size_t)i * 320 + c * 32;
                float ap = 0.f;
#pragma unroll
                for (int o = 0; o < DOUT; ++o) {
                    float4 w0 = wp[o * 2 + 0];
                    float4 w1 = wp[o * 2 + 1];
                    float uh = dot8(w0, w1, ua, ub);
                    ap += uh * vs_lds[bl * V_STRIDE + c * DOUT + o];
                }
                a_lds[bl * A_STRIDE + ic * CC + c] = ap;
            }
            __syncthreads();

            // Phase B: softmax over c, in place (rows = BT*CHUNK = 512)
            for (int r = tid; r < BT * CHUNK; r += NTHR) {
                int rb = r & 63, ric = r >> 6;
                float* row = &a_lds[rb * A_STRIDE + ric * CC];
                float m = row[0];
#pragma unroll
                for (int k = 1; k < CC; ++k) m = fmaxf(m, row[k]);
                float e[CC];
                float sum = 0.f;
#pragma unroll
                for (int k = 0; k < CC; ++k) { e[k] = expf(row[k] - m); sum += e[k]; }
                float inv = 1.f / sum;
#pragma unroll
                for (int k = 0; k < CC; ++k) row[k] = e[k] * inv;
            }
            __syncthreads();
        }

        // Phase C: acc[o] += cij * uh = dot(W, cij*u)
        for (int ic = 0; ic < CHUNK; ++ic) {
            const int i = ibase + ic;
            const float4 ua = u4[(b * II + i) * 2 + 0];
            const float4 ub = u4[(b * II + i) * 2 + 1];
            float cw;
            if constexpr (MODE == 0) cw = 0.1f;
            else cw = a_lds[bl * A_STRIDE + ic * CC + c];
            float4 ta = make_float4(ua.x * cw, ua.y * cw, ua.z * cw, ua.w * cw);
            float4 tb = make_float4(ub.x * cw, ub.y * cw, ub.z * cw, ub.w * cw);
            const float4* wp = W4 + (size_t)i * 320 + c * 32;
#pragma unroll
            for (int o = 0; o < DOUT; ++o) {
                float4 w0 = wp[o * 2 + 0];
                float4 w1 = wp[o * 2 + 1];
                acc[o] += dot8(w0, w1, ta, tb);
            }
        }
        if constexpr (MODE >= 1) __syncthreads();  // a_lds reused next chunk
    }

#pragma unroll
    for (int o = 0; o < DOUT; ++o)
        unsafeAtomicAdd(&s[b * COW + c * DOUT + o], acc[o]);
}

// squash s -> vout, and zero s for the next accumulation pass
__global__ void squash_k(float* __restrict__ s, float* __restrict__ vout)
{
    int t = blockIdx.x * blockDim.x + threadIdx.x;   // (b*10 + c), 0..2559
    if (t >= BB * CC) return;
    float4* sp = (float4*)(s + t * 16);              // b*160 + c*16 == t*16
    float4 x0 = sp[0], x1 = sp[1], x2 = sp[2], x3 = sp[3];
    float sq = x0.x*x0.x + x0.y*x0.y + x0.z*x0.z + x0.w*x0.w
             + x1.x*x1.x + x1.y*x1.y + x1.z*x1.z + x1.w*x1.w
             + x2.x*x2.x + x2.y*x2.y + x2.z*x2.z + x2.w*x2.w
             + x3.x*x3.x + x3.y*x3.y + x3.z*x3.z + x3.w*x3.w;
    float scale = (sq / (1.f + sq)) / sqrtf(sq + 1e-9f);
    float4* vp = (float4*)(vout + t * 16);
    vp[0] = make_float4(x0.x*scale, x0.y*scale, x0.z*scale, x0.w*scale);
    vp[1] = make_float4(x1.x*scale, x1.y*scale, x1.z*scale, x1.w*scale);
    vp[2] = make_float4(x2.x*scale, x2.y*scale, x2.z*scale, x2.w*scale);
    vp[3] = make_float4(x3.x*scale, x3.y*scale, x3.z*scale, x3.w*scale);
    float4 z = make_float4(0.f, 0.f, 0.f, 0.f);
    sp[0] = z; sp[1] = z; sp[2] = z; sp[3] = z;
}

extern "C" void kernel_launch(void* const* d_in, const int* in_sizes, int n_in,
                              void* d_out, int out_size, void* d_ws, size_t ws_size,
                              hipStream_t stream)
{
    const float* u = (const float*)d_in[0];   // [256,2048,8]
    const float* W = (const float*)d_in[1];   // [2048,10,16,8]
    float* out = (float*)d_out;               // [256,10,16]

    float* s  = (float*)d_ws;                 // 40960 f32
    float* v0 = s + BB * COW;                 // 40960 f32
    float* v1 = v0 + BB * COW;                // 40960 f32

    hipMemsetAsync(s, 0, BB * COW * sizeof(float), stream);

    dim3 grid(NISPLIT, BB / BT);
    dim3 blk(NTHR);

    caps_pass<0><<<grid, blk, 0, stream>>>(u, W, nullptr, nullptr, s);
    squash_k<<<(BB * CC + 255) / 256, 256, 0, stream>>>(s, v0);
    caps_pass<1><<<grid, blk, 0, stream>>>(u, W, v0, nullptr, s);
    squash_k<<<(BB * CC + 255) / 256, 256, 0, stream>>>(s, v1);
    caps_pass<2><<<grid, blk, 0, stream>>>(u, W, v0, v1, s);
    squash_k<<<(BB * CC + 255) / 256, 256, 0, stream>>>(s, out);
}

// Round 2
// 431.020 us; speedup vs baseline: 2.3684x; 2.3684x over previous
//
#include <hip/hip_runtime.h>
#include <math.h>

#define BB 256
#define II 2048
#define CC 10
#define DOUT 16
#define COW 160          // C*DOUT
#define BT 64            // b per block (one wave spans 64 b's, c is wave-uniform)
#define CHUNK 2
#define NTHR 640         // BT * CC
#define A_STRIDE (CHUNK*CC + 1)   // 21, odd -> conflict-free lane stride

__device__ __forceinline__ float dot8(const float4& a0, const float4& a1,
                                      const float4& b0, const float4& b1) {
    return a0.x*b0.x + a0.y*b0.y + a0.z*b0.z + a0.w*b0.w
         + a1.x*b1.x + a1.y*b1.y + a1.z*b1.z + a1.w*b1.w;
}

// MODE 0: iter0 (c_ij = 0.1 uniform), single phase.
// MODE 1: iter1 (a = uh.v0, softmax over c, weighted accumulate)
// MODE 2: iter2 (b2 = a0+a1 = uh.(v0+v1), softmax, weighted accumulate)
// Writes per-split partial sums to p[blockIdx.x][b][c][o]; NO atomics.
template<int MODE>
__global__ __launch_bounds__(NTHR, 5)
void caps_pass(const float* __restrict__ u, const float* __restrict__ W,
               const float* __restrict__ v0, const float* __restrict__ v1,
               float* __restrict__ p)
{
    __shared__ float a_lds[2][BT * A_STRIDE];   // ping-pong, 2 x 5.4 KB

    const int tid = threadIdx.x;
    const int bl  = tid & 63;        // b lane
    const int c   = tid >> 6;        // capsule owner 0..9
    const int b   = blockIdx.y * BT + bl;
    const int LEN = II / gridDim.x;  // i's per block
    const int i0  = blockIdx.x * LEN;
    const int nch = LEN / CHUNK;

    // v (or v0+v1) for this thread's (b,c): 16 registers
    float vreg[DOUT];
    if constexpr (MODE >= 1) {
        const float4* vp0 = (const float4*)(v0 + b * COW + c * DOUT);
        const float4* vp1 = (const float4*)(v1 + b * COW + c * DOUT);
#pragma unroll
        for (int q = 0; q < 4; ++q) {
            float4 x = vp0[q];
            if constexpr (MODE == 2) {
                float4 y = vp1[q];
                x.x += y.x; x.y += y.y; x.z += y.z; x.w += y.w;
            }
            vreg[4*q+0] = x.x; vreg[4*q+1] = x.y; vreg[4*q+2] = x.z; vreg[4*q+3] = x.w;
        }
    }

    float acc[DOUT];
#pragma unroll
    for (int o = 0; o < DOUT; ++o) acc[o] = 0.f;

    const float4* u4 = (const float4*)u;
    const float4* W4 = (const float4*)W;

    for (int ch = 0; ch < nch; ++ch) {
        const int ibase = i0 + ch * CHUNK;
        const int par = ch & 1;
        float uh[CHUNK][DOUT];       // u_hat kept in registers A -> C

        // ---- Phase A: compute uh; agreement a = sum_o uh*v ----
#pragma unroll
        for (int ic = 0; ic < CHUNK; ++ic) {
            const int i = ibase + ic;
            const float4 ua = u4[(b * II + i) * 2 + 0];
            const float4 ub = u4[(b * II + i) * 2 + 1];
            const float4* wp = W4 + (size_t)i * 320 + c * 32;  // wave-uniform addr
            if constexpr (MODE >= 1) {
                float ap = 0.f;
#pragma unroll
                for (int o = 0; o < DOUT; ++o) {
                    float4 w0 = wp[2*o + 0];
                    float4 w1 = wp[2*o + 1];
                    uh[ic][o] = dot8(w0, w1, ua, ub);
                    ap += uh[ic][o] * vreg[o];
                }
                a_lds[par][bl * A_STRIDE + ic * CC + c] = ap;
            } else {
#pragma unroll
                for (int o = 0; o < DOUT; ++o) {
                    float4 w0 = wp[2*o + 0];
                    float4 w1 = wp[2*o + 1];
                    acc[o] += dot8(w0, w1, ua, ub);
                }
            }
        }

        if constexpr (MODE >= 1) {
            __syncthreads();
            // ---- Phase B: softmax over c, in place (BT*CHUNK = 128 rows) ----
            if (tid < BT * CHUNK) {
                const int rb = tid & 63, ric = tid >> 6;
                float* row = &a_lds[par][rb * A_STRIDE + ric * CC];
                float m = row[0];
#pragma unroll
                for (int k = 1; k < CC; ++k) m = fmaxf(m, row[k]);
                float e[CC];
                float sum = 0.f;
#pragma unroll
                for (int k = 0; k < CC; ++k) { e[k] = __expf(row[k] - m); sum += e[k]; }
                float inv = 1.f / sum;
#pragma unroll
                for (int k = 0; k < CC; ++k) row[k] = e[k] * inv;
            }
            __syncthreads();
            // ---- Phase C: acc += c_ij * uh (pure register FMA) ----
#pragma unroll
            for (int ic = 0; ic < CHUNK; ++ic) {
                const float cw = a_lds[par][bl * A_STRIDE + ic * CC + c];
#pragma unroll
                for (int o = 0; o < DOUT; ++o) acc[o] += cw * uh[ic][o];
            }
            // no 3rd sync: next chunk uses the other a_lds buffer
        }
    }

    // ---- write partial sums (no atomics) ----
    const float scale = (MODE == 0) ? 0.1f : 1.f;
    float4* pp = (float4*)(p + (size_t)blockIdx.x * (BB * COW) + b * COW + c * DOUT);
#pragma unroll
    for (int q = 0; q < 4; ++q)
        pp[q] = make_float4(acc[4*q+0]*scale, acc[4*q+1]*scale,
                            acc[4*q+2]*scale, acc[4*q+3]*scale);
}

// sum partials over nsplit, squash, write vout. One block per b, 160 threads.
__global__ void reduce_squash(const float* __restrict__ p, int nsplit,
                              float* __restrict__ vout)
{
    __shared__ float sm[COW];
    const int b = blockIdx.x, t = threadIdx.x;
    const float* pb = p + b * COW + t;

    float s0 = 0.f, s1 = 0.f, s2 = 0.f, s3 = 0.f;
    int sp = 0;
    for (; sp + 4 <= nsplit; sp += 4) {
        s0 += pb[(size_t)(sp+0) * BB * COW];
        s1 += pb[(size_t)(sp+1) * BB * COW];
        s2 += pb[(size_t)(sp+2) * BB * COW];
        s3 += pb[(size_t)(sp+3) * BB * COW];
    }
    for (; sp < nsplit; ++sp) s0 += pb[(size_t)sp * BB * COW];
    const float sum = (s0 + s1) + (s2 + s3);

    sm[t] = sum;
    __syncthreads();
    const int c16 = (t >> 4) << 4;
    float sq = 0.f;
#pragma unroll
    for (int k = 0; k < 16; ++k) { const float x = sm[c16 + k]; sq += x * x; }
    const float scale = (sq / (1.f + sq)) * rsqrtf(sq + 1e-9f);
    vout[b * COW + t] = sum * scale;
}

extern "C" void kernel_launch(void* const* d_in, const int* in_sizes, int n_in,
                              void* d_out, int out_size, void* d_ws, size_t ws_size,
                              hipStream_t stream)
{
    const float* u = (const float*)d_in[0];   // [256,2048,8]
    const float* W = (const float*)d_in[1];   // [2048,10,16,8]
    float* out = (float*)d_out;               // [256,10,16]

    const size_t SEG = (size_t)BB * COW;      // 40960 floats
    float* v0 = (float*)d_ws;
    float* v1 = v0 + SEG;
    float* p  = v1 + SEG;

    const size_t avail_f = ws_size / sizeof(float);
    int nsplit = 64;
    while (nsplit > 1 && (2 * SEG + (size_t)nsplit * SEG) > avail_f) nsplit >>= 1;

    dim3 grid(nsplit, BB / BT);
    dim3 blk(NTHR);

    caps_pass<0><<<grid, blk, 0, stream>>>(u, W, nullptr, nullptr, p);
    reduce_squash<<<BB, COW, 0, stream>>>(p, nsplit, v0);
    caps_pass<1><<<grid, blk, 0, stream>>>(u, W, v0, nullptr, p);
    reduce_squash<<<BB, COW, 0, stream>>>(p, nsplit, v1);
    caps_pass<2><<<grid, blk, 0, stream>>>(u, W, v0, v1, p);
    reduce_squash<<<BB, COW, 0, stream>>>(p, nsplit, out);
}

// Round 3
// 378.992 us; speedup vs baseline: 2.6935x; 1.1373x over previous
//
#include <hip/hip_runtime.h>
#include <math.h>

#define BB 256
#define II 2048
#define CC 10
#define DOUT 16
#define COW 160          // C*DOUT
#define BT 32            // b per block
#define NTHR 320         // BT * CC
#define SC 8             // i's staged in LDS per chunk
#define RC 2             // routing chunk (uh registers = RC*16)
#define A_ST (RC*CC+1)   // 21, gcd(21,32)=1 -> conflict-free

__device__ __forceinline__ float dot8(const float4& a0, const float4& a1,
                                      const float4& b0, const float4& b1) {
    return a0.x*b0.x + a0.y*b0.y + a0.z*b0.z + a0.w*b0.w
         + a1.x*b1.x + a1.y*b1.y + a1.z*b1.z + a1.w*b1.w;
}

// MODE 0: iter0 (c_ij = 0.1 uniform).  MODE 1: a = uh.v0.  MODE 2: a = uh.(v0+v1).
// Partial sums to p[blockIdx.x][b][c][o]; no atomics.
template<int MODE>
__global__ __launch_bounds__(NTHR, 4)
void caps_pass(const float* __restrict__ u, const float* __restrict__ W,
               const float* __restrict__ v0, const float* __restrict__ v1,
               float* __restrict__ p)
{
    __shared__ float4 u_lds[SC*2][33];          // [r=(ic,q)][bl], 8448 B
    __shared__ float  a_lds[2][BT * A_ST];      // ping-pong, 2 x 2.7 KB

    const int tid = threadIdx.x;
    const int bl  = tid & 31;        // b lane within block
    const int c   = tid >> 5;        // capsule owner 0..9 (uniform per half-wave)
    const int bbase = blockIdx.y * BT;
    const int b   = bbase + bl;
    const int LEN = II / gridDim.x;
    const int i0  = blockIdx.x * LEN;
    const int nsc = LEN / SC;

    // v (or v0+v1) for this thread's (b,c): 16 registers
    float vreg[DOUT];
    if constexpr (MODE >= 1) {
        const float4* vp0 = (const float4*)(v0 + b * COW + c * DOUT);
        const float4* vp1 = (const float4*)(v1 + b * COW + c * DOUT);
#pragma unroll
        for (int q = 0; q < 4; ++q) {
            float4 x = vp0[q];
            if constexpr (MODE == 2) {
                float4 y = vp1[q];
                x.x += y.x; x.y += y.y; x.z += y.z; x.w += y.w;
            }
            vreg[4*q+0] = x.x; vreg[4*q+1] = x.y; vreg[4*q+2] = x.z; vreg[4*q+3] = x.w;
        }
    }

    float acc[DOUT];
#pragma unroll
    for (int o = 0; o < DOUT; ++o) acc[o] = 0.f;

    const float4* u4 = (const float4*)u;
    const float4* W4 = (const float4*)W;

    for (int sc = 0; sc < nsc; ++sc) {
        const int ib = i0 + sc * SC;

        // ---- stage u[32 b][8 i][8 d] into LDS, line-coalesced ----
        for (int idx = tid; idx < BT * SC * 2; idx += NTHR) {
            const int blb = idx >> 4, r = idx & 15;   // r = ic*2 + q
            u_lds[r][blb] = u4[((size_t)(bbase + blb) * II + ib + (r >> 1)) * 2 + (r & 1)];
        }
        __syncthreads();

        for (int rc = 0; rc < SC / RC; ++rc) {
            const int par = rc & 1;
            float uh[RC][DOUT];

            if constexpr (MODE >= 1) {
                // ---- Phase A: uh + agreement ----
#pragma unroll
                for (int ic = 0; ic < RC; ++ic) {
                    const int il = rc * RC + ic;
                    const int i  = ib + il;
                    const float4 ua = u_lds[il*2 + 0][bl];
                    const float4 ub = u_lds[il*2 + 1][bl];
                    const float4* wp = W4 + (size_t)i * 320 + c * 32;
                    float ap = 0.f;
#pragma unroll
                    for (int o = 0; o < DOUT; ++o) {
                        float4 w0 = wp[2*o + 0];
                        float4 w1 = wp[2*o + 1];
                        uh[ic][o] = dot8(w0, w1, ua, ub);
                        ap += uh[ic][o] * vreg[o];
                    }
                    a_lds[par][bl * A_ST + ic * CC + c] = ap;
                }
                __syncthreads();
                // ---- Phase B: softmax over c (BT*RC = 64 rows) ----
                if (tid < BT * RC) {
                    const int rb = tid & 31, ric = tid >> 5;
                    float* row = &a_lds[par][rb * A_ST + ric * CC];
                    float m = row[0];
#pragma unroll
                    for (int k = 1; k < CC; ++k) m = fmaxf(m, row[k]);
                    float e[CC];
                    float sum = 0.f;
#pragma unroll
                    for (int k = 0; k < CC; ++k) { e[k] = __expf(row[k] - m); sum += e[k]; }
                    float inv = 1.f / sum;
#pragma unroll
                    for (int k = 0; k < CC; ++k) row[k] = e[k] * inv;
                }
                __syncthreads();
                // ---- Phase C: acc += c_ij * uh (register FMA) ----
#pragma unroll
                for (int ic = 0; ic < RC; ++ic) {
                    const float cw = a_lds[par][bl * A_ST + ic * CC + c];
#pragma unroll
                    for (int o = 0; o < DOUT; ++o) acc[o] += cw * uh[ic][o];
                }
                // no 3rd sync: next rc uses the other a_lds buffer
            } else {
#pragma unroll
                for (int ic = 0; ic < RC; ++ic) {
                    const int il = rc * RC + ic;
                    const int i  = ib + il;
                    const float4 ua = u_lds[il*2 + 0][bl];
                    const float4 ub = u_lds[il*2 + 1][bl];
                    const float4* wp = W4 + (size_t)i * 320 + c * 32;
#pragma unroll
                    for (int o = 0; o < DOUT; ++o) {
                        float4 w0 = wp[2*o + 0];
                        float4 w1 = wp[2*o + 1];
                        acc[o] += dot8(w0, w1, ua, ub);
                    }
                }
            }
        }
        __syncthreads();   // protect u_lds (and a_lds parity reuse) across chunks
    }

    // ---- write partial sums ----
    const float scale = (MODE == 0) ? 0.1f : 1.f;
    float4* pp = (float4*)(p + (size_t)blockIdx.x * (BB * COW) + b * COW + c * DOUT);
#pragma unroll
    for (int q = 0; q < 4; ++q)
        pp[q] = make_float4(acc[4*q+0]*scale, acc[4*q+1]*scale,
                            acc[4*q+2]*scale, acc[4*q+3]*scale);
}

// one wave per (b,c): sum partials over nsplit, squash, write vout
__global__ __launch_bounds__(64)
void reduce_squash(const float* __restrict__ p, int nsplit, float* __restrict__ vout)
{
    const int bc = blockIdx.x;          // b*10 + c
    const int b = bc / CC, c = bc % CC;
    const int l = threadIdx.x;
    const int o = l & 15, g = l >> 4;   // 4 split-groups
    const float* base = p + (size_t)b * COW + c * DOUT + o;

    float s = 0.f;
    for (int sp = g; sp < nsplit; sp += 4)
        s += base[(size_t)sp * (BB * COW)];
    s += __shfl_xor(s, 16);
    s += __shfl_xor(s, 32);             // all lanes with same o now hold the total
    float sq = s * s;
    sq += __shfl_xor(sq, 1);
    sq += __shfl_xor(sq, 2);
    sq += __shfl_xor(sq, 4);
    sq += __shfl_xor(sq, 8);            // sum over the 16 o's
    const float scale = (sq / (1.f + sq)) * rsqrtf(sq + 1e-9f);
    if (l < 16) vout[b * COW + c * DOUT + o] = s * scale;
}

extern "C" void kernel_launch(void* const* d_in, const int* in_sizes, int n_in,
                              void* d_out, int out_size, void* d_ws, size_t ws_size,
                              hipStream_t stream)
{
    const float* u = (const float*)d_in[0];   // [256,2048,8]
    const float* W = (const float*)d_in[1];   // [2048,10,16,8]
    float* out = (float*)d_out;               // [256,10,16]

    const size_t SEG = (size_t)BB * COW;      // 40960 floats
    float* v0 = (float*)d_ws;
    float* v1 = v0 + SEG;
    float* p  = v1 + SEG;

    const size_t avail_f = ws_size / sizeof(float);
    int nsplit = 128;                          // LEN = 16
    while (nsplit > 1 && (2 * SEG + (size_t)nsplit * SEG) > avail_f) nsplit >>= 1;

    dim3 grid(nsplit, BB / BT);
    dim3 blk(NTHR);

    caps_pass<0><<<grid, blk, 0, stream>>>(u, W, nullptr, nullptr, p);
    reduce_squash<<<BB * CC, 64, 0, stream>>>(p, nsplit, v0);
    caps_pass<1><<<grid, blk, 0, stream>>>(u, W, v0, nullptr, p);
    reduce_squash<<<BB * CC, 64, 0, stream>>>(p, nsplit, v1);
    caps_pass<2><<<grid, blk, 0, stream>>>(u, W, v0, v1, p);
    reduce_squash<<<BB * CC, 64, 0, stream>>>(p, nsplit, out);
}

// Round 4
// 378.034 us; speedup vs baseline: 2.7003x; 1.0025x over previous
//
#include <hip/hip_runtime.h>
#include <math.h>

#define BB 256
#define II 2048
#define CC 10
#define DOUT 16
#define COW 160          // C*DOUT
#define BT 64            // b per block -> c wave-uniform
#define NTHR 640         // BT * CC
#define SC 4             // i's staged in LDS per chunk
#define RC 2             // i's per routing step (uh regs = RC*16)
#define A_ST (RC*CC+1)   // 21, odd -> conflict-free

__device__ __forceinline__ float dot8(const float4& a0, const float4& a1,
                                      const float4& b0, const float4& b1) {
    return a0.x*b0.x + a0.y*b0.y + a0.z*b0.z + a0.w*b0.w
         + a1.x*b1.x + a1.y*b1.y + a1.z*b1.z + a1.w*b1.w;
}

// MODE 0: c_ij = 0.1 uniform. MODE 1: a = uh.v0. MODE 2: a = uh.(v0+v1).
// Partial sums -> p[blockIdx.x][b][c][o]; no atomics.
template<int MODE>
__global__ __launch_bounds__(NTHR, 5)
void caps_pass(const float* __restrict__ u, const float* __restrict__ W,
               const float* __restrict__ v0, const float* __restrict__ v1,
               float* __restrict__ p)
{
    __shared__ float4 w_lds[SC * CC * 32];   // [il][c][o][q] flat, 20 KB
    __shared__ float4 u_lds[SC * 2][BT];     // [r=il*2+q][bl], 8 KB
    __shared__ float  a_lds[2][BT * A_ST];   // ping-pong, 2 x 5.25 KB

    const int tid = threadIdx.x;
    const int bl  = tid & 63;        // b lane (wave-uniform c)
    const int c   = tid >> 6;        // capsule owner 0..9
    const int bbase = blockIdx.y * BT;
    const int b   = bbase + bl;
    const int LEN = II / gridDim.x;
    const int i0  = blockIdx.x * LEN;
    const int nch = LEN / SC;

    // v (or v0+v1) for this thread's (b,c): 16 registers
    float vreg[DOUT];
    if constexpr (MODE >= 1) {
        const float4* vp0 = (const float4*)(v0 + b * COW + c * DOUT);
        const float4* vp1 = (const float4*)(v1 + b * COW + c * DOUT);
#pragma unroll
        for (int q = 0; q < 4; ++q) {
            float4 x = vp0[q];
            if constexpr (MODE == 2) {
                float4 y = vp1[q];
                x.x += y.x; x.y += y.y; x.z += y.z; x.w += y.w;
            }
            vreg[4*q+0] = x.x; vreg[4*q+1] = x.y; vreg[4*q+2] = x.z; vreg[4*q+3] = x.w;
        }
    }

    float acc[DOUT];
#pragma unroll
    for (int o = 0; o < DOUT; ++o) acc[o] = 0.f;

    const float4* u4 = (const float4*)u;
    const float4* W4 = (const float4*)W;

    for (int ch = 0; ch < nch; ++ch) {
        const int ib = i0 + ch * SC;

        // ---- stage W (SC*320 = 1280 f4, coalesced) and u (512 f4) ----
        {
            const size_t wbase = (size_t)ib * 320;
            w_lds[tid]       = W4[wbase + tid];
            w_lds[tid + 640] = W4[wbase + tid + 640];
            if (tid < BT * SC * 2) {
                const int blb = tid >> 3, r = tid & 7;   // r = il*2 + q
                u_lds[r][blb] = u4[((size_t)(bbase + blb) * II + ib + (r >> 1)) * 2 + (r & 1)];
            }
        }
        __syncthreads();

        for (int rc = 0; rc < SC / RC; ++rc) {
            const int par = rc & 1;
            float uh[RC][DOUT];

            if constexpr (MODE >= 1) {
                // ---- Phase A: uh + agreement (W from LDS, wave-uniform broadcast) ----
#pragma unroll
                for (int ic = 0; ic < RC; ++ic) {
                    const int il = rc * RC + ic;
                    const float4 ua = u_lds[il*2 + 0][bl];
                    const float4 ub = u_lds[il*2 + 1][bl];
                    const float4* wp = &w_lds[(il * CC + c) * 32];
                    float ap = 0.f;
#pragma unroll
                    for (int o = 0; o < DOUT; ++o) {
                        float4 w0 = wp[2*o + 0];
                        float4 w1 = wp[2*o + 1];
                        uh[ic][o] = dot8(w0, w1, ua, ub);
                        ap += uh[ic][o] * vreg[o];
                    }
                    a_lds[par][bl * A_ST + ic * CC + c] = ap;
                }
                __syncthreads();
                // ---- Phase B: softmax over c (BT*RC = 128 rows) ----
                if (tid < BT * RC) {
                    const int rb = tid & 63, ric = tid >> 6;
                    float* row = &a_lds[par][rb * A_ST + ric * CC];
                    float m = row[0];
#pragma unroll
                    for (int k = 1; k < CC; ++k) m = fmaxf(m, row[k]);
                    float e[CC];
                    float sum = 0.f;
#pragma unroll
                    for (int k = 0; k < CC; ++k) { e[k] = __expf(row[k] - m); sum += e[k]; }
                    float inv = 1.f / sum;
#pragma unroll
                    for (int k = 0; k < CC; ++k) row[k] = e[k] * inv;
                }
                __syncthreads();
                // ---- Phase C: acc += c_ij * uh (register FMA) ----
#pragma unroll
                for (int ic = 0; ic < RC; ++ic) {
                    const float cw = a_lds[par][bl * A_ST + ic * CC + c];
#pragma unroll
                    for (int o = 0; o < DOUT; ++o) acc[o] += cw * uh[ic][o];
                }
                // next rc uses the other a_lds buffer -> no 3rd sync
            } else {
#pragma unroll
                for (int ic = 0; ic < RC; ++ic) {
                    const int il = rc * RC + ic;
                    const float4 ua = u_lds[il*2 + 0][bl];
                    const float4 ub = u_lds[il*2 + 1][bl];
                    const float4* wp = &w_lds[(il * CC + c) * 32];
#pragma unroll
                    for (int o = 0; o < DOUT; ++o) {
                        float4 w0 = wp[2*o + 0];
                        float4 w1 = wp[2*o + 1];
                        acc[o] += dot8(w0, w1, ua, ub);
                    }
                }
            }
        }
        __syncthreads();   // protect w_lds/u_lds before restaging
    }

    // ---- write partial sums ----
    const float scale = (MODE == 0) ? 0.1f : 1.f;
    float4* pp = (float4*)(p + (size_t)blockIdx.x * (BB * COW) + b * COW + c * DOUT);
#pragma unroll
    for (int q = 0; q < 4; ++q)
        pp[q] = make_float4(acc[4*q+0]*scale, acc[4*q+1]*scale,
                            acc[4*q+2]*scale, acc[4*q+3]*scale);
}

// one wave per (b,c): sum partials over nsplit, squash, write vout
__global__ __launch_bounds__(64)
void reduce_squash(const float* __restrict__ p, int nsplit, float* __restrict__ vout)
{
    const int bc = blockIdx.x;          // b*10 + c
    const int b = bc / CC, c = bc % CC;
    const int l = threadIdx.x;
    const int o = l & 15, g = l >> 4;   // 4 split-groups
    const float* base = p + (size_t)b * COW + c * DOUT + o;

    float s = 0.f;
    for (int sp = g; sp < nsplit; sp += 4)
        s += base[(size_t)sp * (BB * COW)];
    s += __shfl_xor(s, 16);
    s += __shfl_xor(s, 32);             // lanes with same o hold the total
    float sq = s * s;
    sq += __shfl_xor(sq, 1);
    sq += __shfl_xor(sq, 2);
    sq += __shfl_xor(sq, 4);
    sq += __shfl_xor(sq, 8);            // sum over the 16 o's
    const float scale = (sq / (1.f + sq)) * rsqrtf(sq + 1e-9f);
    if (l < 16) vout[b * COW + c * DOUT + o] = s * scale;
}

extern "C" void kernel_launch(void* const* d_in, const int* in_sizes, int n_in,
                              void* d_out, int out_size, void* d_ws, size_t ws_size,
                              hipStream_t stream)
{
    const float* u = (const float*)d_in[0];   // [256,2048,8]
    const float* W = (const float*)d_in[1];   // [2048,10,16,8]
    float* out = (float*)d_out;               // [256,10,16]

    const size_t SEG = (size_t)BB * COW;      // 40960 floats
    float* v0 = (float*)d_ws;
    float* v1 = v0 + SEG;
    float* p  = v1 + SEG;

    const size_t avail_f = ws_size / sizeof(float);
    int nsplit = 128;                          // LEN = 16
    while (nsplit > 1 && (2 * SEG + (size_t)nsplit * SEG) > avail_f) nsplit >>= 1;

    dim3 grid(nsplit, BB / BT);
    dim3 blk(NTHR);

    caps_pass<0><<<grid, blk, 0, stream>>>(u, W, nullptr, nullptr, p);
    reduce_squash<<<BB * CC, 64, 0, stream>>>(p, nsplit, v0);
    caps_pass<1><<<grid, blk, 0, stream>>>(u, W, v0, nullptr, p);
    reduce_squash<<<BB * CC, 64, 0, stream>>>(p, nsplit, v1);
    caps_pass<2><<<grid, blk, 0, stream>>>(u, W, v0, v1, p);
    reduce_squash<<<BB * CC, 64, 0, stream>>>(p, nsplit, out);
}

// Round 5
// 242.676 us; speedup vs baseline: 4.2065x; 1.5578x over previous
//
#include <hip/hip_runtime.h>
#include <math.h>

#define BB 256
#define II 2048
#define CC 10
#define DOUT 16
#define COW 160          // C*DOUT
#define BT 64            // b per block -> c wave-uniform
#define NTHR 640         // BT * CC
#define SC 8             // i's staged per chunk
#define RC 2             // i's per routing step (uh regs = RC*16)
#define A_ST (RC*CC+1)   // 21, odd -> conflict-free lane stride

__device__ __forceinline__ float dot8(const float4& a0, const float4& a1,
                                      const float4& b0, const float4& b1) {
    return a0.x*b0.x + a0.y*b0.y + a0.z*b0.z + a0.w*b0.w
         + a1.x*b1.x + a1.y*b1.y + a1.z*b1.z + a1.w*b1.w;
}

// MODE 0: c_ij = 0.1 uniform. MODE 1: a = uh.v0. MODE 2: a = uh.(v0+v1).
// Partial sums -> p[blockIdx.x][b][c][o]; no atomics.
// W is read directly from global with a wave-uniform (readfirstlane) address
// -> scalar s_load path, L2-resident. u staged through LDS (coalesced).
template<int MODE>
__global__ __launch_bounds__(NTHR, 5)
void caps_pass(const float* __restrict__ u, const float* __restrict__ W,
               const float* __restrict__ v0, const float* __restrict__ v1,
               float* __restrict__ p)
{
    __shared__ float4 u_lds[SC*2][65];       // [r=il*2+q][bl], padded, 16.6 KB
    __shared__ float  a_lds[2][BT * A_ST];   // ping-pong, 2 x 5.25 KB

    const int tid = threadIdx.x;
    const int bl  = tid & 63;                          // b lane
    const int c   = __builtin_amdgcn_readfirstlane(tid >> 6);  // wave-uniform capsule
    const int bbase = blockIdx.y * BT;
    const int b   = bbase + bl;
    const int LEN = II / gridDim.x;
    const int i0  = blockIdx.x * LEN;
    const int nch = LEN / SC;

    // v (or v0+v1) for this thread's (b,c): 16 registers
    float vreg[DOUT];
    if constexpr (MODE >= 1) {
        const float4* vp0 = (const float4*)(v0 + b * COW + c * DOUT);
        const float4* vp1 = (const float4*)(v1 + b * COW + c * DOUT);
#pragma unroll
        for (int q = 0; q < 4; ++q) {
            float4 x = vp0[q];
            if constexpr (MODE == 2) {
                float4 y = vp1[q];
                x.x += y.x; x.y += y.y; x.z += y.z; x.w += y.w;
            }
            vreg[4*q+0] = x.x; vreg[4*q+1] = x.y; vreg[4*q+2] = x.z; vreg[4*q+3] = x.w;
        }
    }

    float acc[DOUT];
#pragma unroll
    for (int o = 0; o < DOUT; ++o) acc[o] = 0.f;

    const float4* u4 = (const float4*)u;
    const float4* W4 = (const float4*)W;

    for (int chk = 0; chk < nch; ++chk) {
        const int ib = i0 + chk * SC;

        // ---- stage u: lanes cover contiguous 256B per b (coalesced) ----
        for (int idx = tid; idx < BT * SC * 2; idx += NTHR) {
            const int r = idx & 15, blb = idx >> 4;    // r = il*2 + q
            u_lds[r][blb] = u4[((size_t)(bbase + blb) * II + ib + (r >> 1)) * 2 + (r & 1)];
        }
        __syncthreads();

        for (int rc = 0; rc < SC / RC; ++rc) {
            const int par = rc & 1;
            float uh[RC][DOUT];

            // ---- Phase A: uh (W via wave-uniform scalar loads) ----
#pragma unroll
            for (int ic = 0; ic < RC; ++ic) {
                const int il = rc * RC + ic;
                const float4 ua = u_lds[il*2 + 0][bl];
                const float4 ub = u_lds[il*2 + 1][bl];
                const float4* wp = W4 + ((size_t)(ib + il) * CC + c) * 32;  // uniform
                if constexpr (MODE >= 1) {
                    float ap = 0.f;
#pragma unroll
                    for (int o = 0; o < DOUT; ++o) {
                        float4 w0 = wp[2*o + 0];
                        float4 w1 = wp[2*o + 1];
                        uh[ic][o] = dot8(w0, w1, ua, ub);
                        ap += uh[ic][o] * vreg[o];
                    }
                    a_lds[par][bl * A_ST + ic * CC + c] = ap;
                } else {
#pragma unroll
                    for (int o = 0; o < DOUT; ++o) {
                        float4 w0 = wp[2*o + 0];
                        float4 w1 = wp[2*o + 1];
                        acc[o] += dot8(w0, w1, ua, ub);
                    }
                }
            }

            if constexpr (MODE >= 1) {
                __syncthreads();   // a rows complete (single barrier per rc)
                // ---- per-thread softmax over c + weighted accumulate ----
#pragma unroll
                for (int ic = 0; ic < RC; ++ic) {
                    const float* row = &a_lds[par][bl * A_ST + ic * CC];
                    float m = row[0];
#pragma unroll
                    for (int k = 1; k < CC; ++k) m = fmaxf(m, row[k]);
                    float sum = 0.f;
#pragma unroll
                    for (int k = 0; k < CC; ++k) sum += __expf(row[k] - m);
                    const float cw = __expf(row[c] - m) / sum;
#pragma unroll
                    for (int o = 0; o < DOUT; ++o) acc[o] += cw * uh[ic][o];
                }
                // ping-pong a_lds -> no trailing barrier needed
            }
        }
        if constexpr (MODE == 0) __syncthreads();  // protect u_lds before restage
    }

    // ---- write partial sums ----
    const float scale = (MODE == 0) ? 0.1f : 1.f;
    float4* pp = (float4*)(p + (size_t)blockIdx.x * (BB * COW) + b * COW + c * DOUT);
#pragma unroll
    for (int q = 0; q < 4; ++q)
        pp[q] = make_float4(acc[4*q+0]*scale, acc[4*q+1]*scale,
                            acc[4*q+2]*scale, acc[4*q+3]*scale);
}

// one wave per (b,c): sum partials over nsplit, squash, write vout
__global__ __launch_bounds__(64)
void reduce_squash(const float* __restrict__ p, int nsplit, float* __restrict__ vout)
{
    const int bc = blockIdx.x;          // b*10 + c
    const int b = bc / CC, c = bc % CC;
    const int l = threadIdx.x;
    const int o = l & 15, g = l >> 4;   // 4 split-groups
    const float* base = p + (size_t)b * COW + c * DOUT + o;

    float s = 0.f;
    for (int sp = g; sp < nsplit; sp += 4)
        s += base[(size_t)sp * (BB * COW)];
    s += __shfl_xor(s, 16);
    s += __shfl_xor(s, 32);             // lanes with same o hold the total
    float sq = s * s;
    sq += __shfl_xor(sq, 1);
    sq += __shfl_xor(sq, 2);
    sq += __shfl_xor(sq, 4);
    sq += __shfl_xor(sq, 8);            // sum over the 16 o's
    const float scale = (sq / (1.f + sq)) * rsqrtf(sq + 1e-9f);
    if (l < 16) vout[b * COW + c * DOUT + o] = s * scale;
}

extern "C" void kernel_launch(void* const* d_in, const int* in_sizes, int n_in,
                              void* d_out, int out_size, void* d_ws, size_t ws_size,
                              hipStream_t stream)
{
    const float* u = (const float*)d_in[0];   // [256,2048,8]
    const float* W = (const float*)d_in[1];   // [2048,10,16,8]
    float* out = (float*)d_out;               // [256,10,16]

    const size_t SEG = (size_t)BB * COW;      // 40960 floats
    float* v0 = (float*)d_ws;
    float* v1 = v0 + SEG;
    float* p  = v1 + SEG;

    const size_t avail_f = ws_size / sizeof(float);
    int nsplit = 128;                          // LEN = 16
    while (nsplit > 1 && (2 * SEG + (size_t)nsplit * SEG) > avail_f) nsplit >>= 1;

    dim3 grid(nsplit, BB / BT);
    dim3 blk(NTHR);

    caps_pass<0><<<grid, blk, 0, stream>>>(u, W, nullptr, nullptr, p);
    reduce_squash<<<BB * CC, 64, 0, stream>>>(p, nsplit, v0);
    caps_pass<1><<<grid, blk, 0, stream>>>(u, W, v0, nullptr, p);
    reduce_squash<<<BB * CC, 64, 0, stream>>>(p, nsplit, v1);
    caps_pass<2><<<grid, blk, 0, stream>>>(u, W, v0, v1, p);
    reduce_squash<<<BB * CC, 64, 0, stream>>>(p, nsplit, out);
}